// Round 17
// baseline (288.487 us; speedup 1.0000x reference)
//
#include <hip/hip_runtime.h>
#include <math.h>

typedef __bf16 bf16;
typedef __attribute__((ext_vector_type(2))) __bf16 bf16x2;
typedef __attribute__((ext_vector_type(4))) __bf16 bf16x4;
typedef __attribute__((ext_vector_type(8))) __bf16 bf16x8;
typedef __attribute__((ext_vector_type(4))) float f32x4;

#define GLD16(g, l) __builtin_amdgcn_global_load_lds( \
    (const __attribute__((address_space(1))) void*)(g), \
    (__attribute__((address_space(3))) void*)(l), 16, 0, 0)

template<int N> __device__ __forceinline__ void wait_vm() {
  static_assert(N == 0 || N == 4 || N == 6, "");
  if constexpr (N == 0) asm volatile("s_waitcnt vmcnt(0)" ::: "memory");
  else if constexpr (N == 4) asm volatile("s_waitcnt vmcnt(4)" ::: "memory");
  else asm volatile("s_waitcnt vmcnt(6)" ::: "memory");
}

// ---------------- fused prologue: casts + bias concat + rope table ----------------
__global__ void prep_kernel(const float* __restrict__ x,
                            const float* __restrict__ Wq, const float* __restrict__ Wk,
                            const float* __restrict__ Wv, const float* __restrict__ Wo,
                            const float* __restrict__ bq, const float* __restrict__ bk,
                            const float* __restrict__ bv,
                            bf16* __restrict__ xb, bf16* __restrict__ wqkv, bf16* __restrict__ wob,
                            float* __restrict__ biasq, float* __restrict__ cost, float* __restrict__ sint) {
  const int bid = blockIdx.x, t = threadIdx.x;
  if (bid < 24576) {
    const float* src;
    bf16* dst;
    int i;
    if (bid < 8192)       { src = x;  dst = xb;                    i = bid * 256 + t; }
    else if (bid < 12288) { src = Wq; dst = wqkv;                  i = (bid - 8192) * 256 + t; }
    else if (bid < 16384) { src = Wk; dst = wqkv + 2048 * 2048;    i = (bid - 12288) * 256 + t; }
    else if (bid < 20480) { src = Wv; dst = wqkv + 2 * 2048 * 2048; i = (bid - 16384) * 256 + t; }
    else                  { src = Wo; dst = wob;                   i = (bid - 20480) * 256 + t; }
    float4 f = ((const float4*)src)[i];
    bf16x4 o;
    o[0] = (bf16)f.x; o[1] = (bf16)f.y; o[2] = (bf16)f.z; o[3] = (bf16)f.w;
    ((bf16x4*)dst)[i] = o;
  } else if (bid < 25088) {
    int i = (bid - 24576) * 256 + t;  // S*64
    int s = i >> 6, d = i & 63;
    float inv = powf(10000.0f, -(float)d / 64.0f);
    float ang = (float)s * inv;
    cost[i] = cosf(ang);
    sint[i] = sinf(ang);
  } else {
    int i = (bid - 25088) * 256 + t;  // 6144
    biasq[i] = (i < 2048) ? bq[i] : (i < 4096 ? bk[i - 2048] : bv[i - 4096]);
  }
}

// ---------------- fused RoPE-K + V-transpose (region-switched) ----------------
__global__ void rope_tv_kernel(const bf16* __restrict__ qkv,
                               const float* __restrict__ cost, const float* __restrict__ sint,
                               bf16* __restrict__ kr, bf16* __restrict__ vt) {
  __shared__ bf16 Vl[64 * 72];
  const int t = threadIdx.x;
  if (blockIdx.x < 4096) {
    int idx = blockIdx.x * 256 + t;  // (b,s,h,dp), dp<16 -> d0=dp*4
    int dp = idx & 15;
    int h = (idx >> 4) & 15;
    int s = (idx >> 8) & 2047;
    int b = idx >> 19;
    int d0 = dp * 4;
    const bf16* row = qkv + ((size_t)(b * 2048 + s) * 6144) + 2048 + h * 128;
    bf16x4 klo = *(const bf16x4*)&row[d0];
    bf16x4 khi = *(const bf16x4*)&row[d0 + 64];
    float4 c4 = *(const float4*)&cost[(s << 6) + d0];
    float4 s4 = *(const float4*)&sint[(s << 6) + d0];
    float cf[4] = {c4.x, c4.y, c4.z, c4.w};
    float sf[4] = {s4.x, s4.y, s4.z, s4.w};
    bf16x4 olo, ohi;
#pragma unroll
    for (int j = 0; j < 4; ++j) {
      float kl = (float)klo[j], kh = (float)khi[j];
      olo[j] = (bf16)(kl * cf[j] - kh * sf[j]);
      ohi[j] = (bf16)(kh * cf[j] + kl * sf[j]);
    }
    bf16* orow = kr + (((size_t)(b * 16 + h) * 2048 + s) * 128);
    *(bf16x4*)&orow[d0] = olo;
    *(bf16x4*)&orow[d0 + 64] = ohi;
  } else {
    int vbid = blockIdx.x - 4096;   // 2048 blocks
    const int dt = vbid & 1, st = (vbid >> 1) & 31, bh = vbid >> 6;
    const int b = bh >> 4, h = bh & 15;
    const bf16* src = qkv + ((size_t)(b * 2048 + st * 64) * 6144) + 4096 + h * 128 + dt * 64;
    bf16* dst = vt + ((size_t)bh * 128 + dt * 64) * 2048 + st * 64;
#pragma unroll
    for (int i = 0; i < 2; ++i) {
      int c = i * 256 + t;
      int r = c >> 3, c0 = (c & 7) * 8;
      *(bf16x8*)&Vl[r * 72 + c0] = *(const bf16x8*)&src[(size_t)r * 6144 + c0];
    }
    __syncthreads();
#pragma unroll
    for (int i = 0; i < 2; ++i) {
      int c = i * 256 + t;
      int r = c >> 3, c0 = (c & 7) * 8;
      bf16x8 v;
#pragma unroll
      for (int j = 0; j < 8; ++j) v[j] = Vl[(c0 + j) * 72 + r];
      *(bf16x8*)&dst[(size_t)r * 2048 + c0] = v;
    }
  }
}

// ---------------- GEMM 128xBN kk-split 2-phase, 4-wave, 2 blocks/CU ----------------
// (unchanged from R9 — proven)
template<int BN, bool OUT_BF16>
__global__ __launch_bounds__(256, 2)
void gemm4w_kernel(const bf16* __restrict__ A, const bf16* __restrict__ B,
                   const float* __restrict__ bias, void* __restrict__ Cp,
                   int M, int N, int K) {
  constexpr int NB = BN / 64;   // B LDS units
  constexpr int NR = BN / 32;   // n-tiles per wave
  __shared__ bf16 Al[2][128 * 64];
  __shared__ bf16 Bl[2][NB][64 * 64];
  const int t = threadIdx.x;
  const int wid = t >> 6, lane = t & 63;
  const int wr = wid >> 1, wc = wid & 1;
  const int lr = lane & 15, lk = lane >> 4;
  const int flat = (int)blockIdx.x;
  const int xcd = flat & 7, r0 = flat >> 3;
  const int tm = xcd * 4 + (r0 & 3);
  const int tn = r0 >> 2;
  const bf16* Ab = A + (size_t)tm * 128 * K;
  const bf16* Bb = B + (size_t)tn * BN * K;
  const int NT = K >> 6;

  auto stageA = [&](int bp, int h, int kt) {   // one 64x64 half, 2 insts/thread
#pragma unroll
    for (int q = 0; q < 2; ++q) {
      int e = q * 256 + t;
      int r = e >> 3, c = e & 7;
      GLD16(Ab + (size_t)(h * 64 + r) * K + kt * 64 + ((c ^ (r & 7)) << 3),
            &Al[bp][h * 4096 + e * 8]);
    }
  };
  auto stageB = [&](int bp, int unit, int kt) {  // one 64x64 unit, 2 insts/thread
#pragma unroll
    for (int q = 0; q < 2; ++q) {
      int e = q * 256 + t;
      int r = e >> 3, c = e & 7;
      GLD16(Bb + (size_t)(unit * 64 + r) * K + kt * 64 + ((c ^ (r & 7)) << 3),
            &Bl[bp][unit][e * 8]);
    }
  };
  auto readA = [&](int bp, int m, int kk) -> bf16x8 {
    int row = wr * 64 + m * 16 + lr;
    return *(const bf16x8*)&Al[bp][row * 64 + ((((kk << 2) | lk) ^ (row & 7)) << 3)];
  };
  auto readB = [&](int bp, int n, int kk) -> bf16x8 {
    int rb = wc * (NR * 16) + n * 16 + lr;
    return *(const bf16x8*)&Bl[bp][rb >> 6][(rb & 63) * 64 + ((((kk << 2) | lk) ^ (rb & 7)) << 3)];
  };

  f32x4 acc[4][NR] = {};

  // prologue: B(0), A(0), B(1); leave B(1) (2*NB insts) in flight
#pragma unroll
  for (int un = 0; un < NB; ++un) stageB(0, un, 0);
  stageA(0, 0, 0); stageA(0, 1, 0);
  if (NT > 1) {
#pragma unroll
    for (int un = 0; un < NB; ++un) stageB(1, un, 1);
    wait_vm<2 * NB>();
  } else {
    wait_vm<0>();
  }
  __builtin_amdgcn_s_barrier();
  __builtin_amdgcn_sched_barrier(0);

  for (int u = 0; u < NT; ++u) {
    const int p = u & 1;
    // ---- phase 0 head: all B frags + A(kk=0); stage A(u+1) ----
    bf16x8 bfr[NR][2], afr[4];
#pragma unroll
    for (int n = 0; n < NR; ++n)
#pragma unroll
      for (int kk = 0; kk < 2; ++kk) bfr[n][kk] = readB(p, n, kk);
#pragma unroll
    for (int m = 0; m < 4; ++m) afr[m] = readA(p, m, 0);
    if (u + 1 < NT) { stageA(p ^ 1, 0, u + 1); stageA(p ^ 1, 1, u + 1); }
    __builtin_amdgcn_s_barrier();
    asm volatile("s_waitcnt lgkmcnt(0)" ::: "memory");
    __builtin_amdgcn_sched_barrier(0);
    __builtin_amdgcn_s_setprio(1);
#pragma unroll
    for (int m = 0; m < 4; ++m)
#pragma unroll
      for (int n = 0; n < NR; ++n)
        acc[m][n] = __builtin_amdgcn_mfma_f32_16x16x32_bf16(afr[m], bfr[n][0], acc[m][n], 0, 0, 0);
    __builtin_amdgcn_s_setprio(0);
    __builtin_amdgcn_sched_barrier(0);
    // ---- phase 1 head: A(kk=1); stage B(u+2) (Bl[p] reads drained at ph0 lgkm) ----
#pragma unroll
    for (int m = 0; m < 4; ++m) afr[m] = readA(p, m, 1);
    if (u + 2 < NT) {
#pragma unroll
      for (int un = 0; un < NB; ++un) stageB(p, un, u + 2);
    }
    __builtin_amdgcn_s_barrier();
    asm volatile("s_waitcnt lgkmcnt(0)" ::: "memory");
    __builtin_amdgcn_sched_barrier(0);
    __builtin_amdgcn_s_setprio(1);
#pragma unroll
    for (int m = 0; m < 4; ++m)
#pragma unroll
      for (int n = 0; n < NR; ++n)
        acc[m][n] = __builtin_amdgcn_mfma_f32_16x16x32_bf16(afr[m], bfr[n][1], acc[m][n], 0, 0, 0);
    __builtin_amdgcn_s_setprio(0);
    __builtin_amdgcn_sched_barrier(0);
    if (u + 2 < NT) { wait_vm<2 * NB>(); }
    else            { wait_vm<0>(); }
    __builtin_amdgcn_s_barrier();
    __builtin_amdgcn_sched_barrier(0);
  }

  const int rbase = tm * 128 + wr * 64, cbase = tn * BN + wc * (NR * 16);
#pragma unroll
  for (int n = 0; n < NR; ++n) {
    int col = cbase + n * 16 + lr;
    float bvl = bias[col];
#pragma unroll
    for (int m = 0; m < 4; ++m) {
#pragma unroll
      for (int rr = 0; rr < 4; ++rr) {
        int row = rbase + m * 16 + lk * 4 + rr;
        float v = acc[m][n][rr] + bvl;
        if (OUT_BF16) ((bf16*)Cp)[(size_t)row * N + col] = (bf16)v;
        else          ((float*)Cp)[(size_t)row * N + col] = v;
      }
    }
  }
}

// ---------------- causal flash attention: KVBLK=32, 4 blocks/CU ----------------
// R12's proven structure (double-buffered prefetch, fast-path softmax, deferred sum,
// balanced pairing) with HALF-size KV tiles: LDS = 2x8K (K) + 2x8K (V^T) + 4x1K (P)
// = 36 KB -> 4 co-resident blocks/CU (vs 2). Iterations double (66) but per-iteration
// chain shrinks and 2x waves hide it. Per-wave state SHRINKS (sa[2], p[2][4]).
// Swizzles: K chunk ^= kv&7 (unchanged); V^T [128][32] chunk ^= d&3; P [16][32]
// chunk ^= row>>2 (also fixes the old 4-way P-write alias).
// Launch bounds (256,3): proven 112-VGPR regime (arg>=4 caps VGPR at 64 -> spill).
__global__ __launch_bounds__(256, 3)
void attn_kernel(const bf16* __restrict__ qkv, const bf16* __restrict__ Kc,
                 const bf16* __restrict__ Vtg, const float* __restrict__ cost,
                 const float* __restrict__ sint, bf16* __restrict__ O, int S) {
  __shared__ bf16 Kl[2][32 * 128];  // [kv][d], 16B chunks XOR-swizzled by kv&7
  __shared__ bf16 Vt[2][128 * 32];  // [d][kv], 16B chunks XOR-swizzled by d&3
  __shared__ bf16 Pl[4][16 * 32];   // per-wave P, 16B chunks XOR-swizzled by row>>2
  const int t = threadIdx.x, wid = t >> 6, lane = t & 63;
  const int lr = lane & 15, lk = lane >> 4;
  const int flat = (int)blockIdx.x;
  const int xcd = flat & 7, kk2 = flat >> 3;     // kk2 0..63
  const int bh = xcd * 4 + (kk2 >> 4);           // 4 bh per XCD
  const int b = bh >> 4, h = bh & 15;
  const int NQ = S >> 6;
  const int qtA = kk2 & 15, qtB = NQ - 1 - qtA;
  const int ktA = 2 * (qtA + 1), ktB = 2 * (qtB + 1), total = ktA + ktB;  // == 2*(NQ+1)
  const bf16* Kb = Kc + (size_t)bh * S * 128;
  const bf16* Vb = Vtg + (size_t)bh * 128 * S;
  const float SCL2 = 0.12752040147f;  // (1/sqrt(128)) * log2(e) -> log2-domain logits

  bf16x8 qf[4];
  auto loadQ = [&](int q0) {
    int qrow = q0 + wid * 16 + lr;
    const bf16* qp = qkv + (size_t)(b * 2048 + qrow) * 6144 + h * 128;
    bf16x8 raw[4];
#pragma unroll
    for (int kb = 0; kb < 4; ++kb) raw[kb] = *(const bf16x8*)&qp[kb * 32 + lk * 8];
#pragma unroll
    for (int kb = 0; kb < 4; ++kb) {
      const float* cb = cost + (qrow << 6) + ((kb & 1) << 5) + lk * 8;
      const float* sb = sint + (qrow << 6) + ((kb & 1) << 5) + lk * 8;
#pragma unroll
      for (int j = 0; j < 8; ++j) {
        float qv = (float)raw[kb][j];
        float qo = (float)raw[kb ^ 2][j];
        float rot = (kb < 2) ? -qo : qo;   // d<64 <=> kb<2
        qf[kb][j] = (bf16)((qv * cb[j] + rot * sb[j]) * SCL2);
      }
    }
  };
  // stage one 32-kv tile: K 8KB (512 chunks) + V^T 8KB (512 chunks), 4 GLD16/thread
  auto stage = [&](int buf, int kv0) {
#pragma unroll
    for (int c = 0; c < 2; ++c) {
      int fc = c * 256 + t;
      int kvr = fc >> 4, cc = fc & 15;      // K: [32 rows][16 chunks]
      GLD16(Kb + (size_t)(kv0 + kvr) * 128 + (cc ^ (kvr & 7)) * 8, &Kl[buf][fc * 8]);
      int dr = fc >> 2, c2 = fc & 3;        // V^T: [128 rows][4 chunks]
      GLD16(Vb + (size_t)dr * S + kv0 + (c2 ^ (dr & 3)) * 8, &Vt[buf][fc * 8]);
    }
  };

  f32x4 o[8] = {};
  float mrun[4], lrun[4];
#pragma unroll
  for (int r = 0; r < 4; ++r) { mrun[r] = -INFINITY; lrun[r] = 0.f; }

  loadQ(qtA * 64);
  stage(0, 0);
  __syncthreads();  // tile 0 resident
  int cur = 0;
  for (int ti = 0; ti < total; ++ti) {
    if (ti + 1 < total) {
      int tn = ti + 1;
      stage(cur ^ 1, ((tn < ktA) ? tn : tn - ktA) * 32);
    }
    __builtin_amdgcn_sched_barrier(0);
    const bool isA = ti < ktA;
    const int tt = isA ? ti : ti - ktA;
    const int kt = isA ? ktA : ktB;
    const int q0 = (isA ? qtA : qtB) * 64;
    const int kv0 = tt * 32;
    f32x4 sa[2];
    __builtin_amdgcn_s_setprio(1);
#pragma unroll
    for (int n = 0; n < 2; ++n) {
      sa[n] = (f32x4){0.f, 0.f, 0.f, 0.f};
      int kvl = n * 16 + lr;
#pragma unroll
      for (int kb = 0; kb < 4; ++kb) {
        bf16x8 kf = *(const bf16x8*)&Kl[cur][kvl * 128 + (((kb << 2) | lk) ^ (kvl & 7)) * 8];
        sa[n] = __builtin_amdgcn_mfma_f32_16x16x32_bf16(qf[kb], kf, sa[n], 0, 0, 0);
      }
    }
    __builtin_amdgcn_s_setprio(0);
    // ---- fast-path softmax (log2 domain) ----
    float p[2][4];
    float tmax[4] = {-INFINITY, -INFINITY, -INFINITY, -INFINITY};
    const bool diag = (tt >= kt - 2);   // diagonal 64x64 block spans the last TWO 32-kv tiles
#pragma unroll
    for (int n = 0; n < 2; ++n)
#pragma unroll
      for (int r = 0; r < 4; ++r) {
        float s = sa[n][r];
        if (diag) {
          int kvg = kv0 + n * 16 + lr;
          int qg = q0 + wid * 16 + lk * 4 + r;
          if (kvg > qg) s = -INFINITY;
        }
        p[n][r] = s;
        tmax[r] = fmaxf(tmax[r], s);   // per-thread only (4 values)
      }
    bool need = false;
#pragma unroll
    for (int r = 0; r < 4; ++r) need = need || (tmax[r] > mrun[r] + 6.0f);
    if (__any(need)) {   // slow path: full cross-lane max + rescale (rare)
#pragma unroll
      for (int r = 0; r < 4; ++r) {
#pragma unroll
        for (int off = 1; off < 16; off <<= 1)
          tmax[r] = fmaxf(tmax[r], __shfl_xor(tmax[r], off));
        float mnew = fmaxf(mrun[r], tmax[r]);
        float alpha = exp2f(mrun[r] - mnew);
        mrun[r] = mnew;
        lrun[r] *= alpha;
#pragma unroll
        for (int n8 = 0; n8 < 8; ++n8) o[n8][r] *= alpha;
      }
    }
#pragma unroll
    for (int n = 0; n < 2; ++n)
#pragma unroll
      for (int r = 0; r < 4; ++r)
        p[n][r] = exp2f(p[n][r] - mrun[r]);   // bounded by 2^6
    // write P and launch PV immediately (sum tree deferred)
#pragma unroll
    for (int n = 0; n < 2; ++n)
#pragma unroll
      for (int r = 0; r < 4; ++r) {
        int row = lk * 4 + r, col = n * 16 + lr;
        Pl[wid][(row * 32 + col) ^ ((row >> 2) << 3)] = (bf16)p[n][r];
      }
    __builtin_amdgcn_s_setprio(1);
    {
      bf16x8 pf = *(const bf16x8*)&Pl[wid][(lr * 32 + lk * 8) ^ ((lr >> 2) << 3)];
#pragma unroll
      for (int n8 = 0; n8 < 8; ++n8) {
        int dcol = n8 * 16 + lr;
        bf16x8 vf = *(const bf16x8*)&Vt[cur][(dcol * 32 + lk * 8) ^ ((dcol & 3) << 3)];
        o[n8] = __builtin_amdgcn_mfma_f32_16x16x32_bf16(pf, vf, o[n8], 0, 0, 0);
      }
    }
    __builtin_amdgcn_s_setprio(0);
    // ---- deferred row-sum (overlaps PV on the DS/VALU pipes) ----
    {
      float rsum[4];
#pragma unroll
      for (int r = 0; r < 4; ++r) {
        rsum[r] = p[0][r] + p[1][r];
#pragma unroll
        for (int off = 1; off < 16; off <<= 1)
          rsum[r] += __shfl_xor(rsum[r], off);
        lrun[r] += rsum[r];
      }
    }
    if (ti == ktA - 1) {
#pragma unroll
      for (int r = 0; r < 4; ++r) {
        float rl = 1.0f / lrun[r];
        int row = qtA * 64 + wid * 16 + lk * 4 + r;
        size_t base = ((size_t)(b * S + row)) * 2048 + h * 128;
#pragma unroll
        for (int n8 = 0; n8 < 8; ++n8)
          O[base + n8 * 16 + lr] = (bf16)(o[n8][r] * rl);
      }
#pragma unroll
      for (int n8 = 0; n8 < 8; ++n8) o[n8] = (f32x4){0.f, 0.f, 0.f, 0.f};
#pragma unroll
      for (int r = 0; r < 4; ++r) { mrun[r] = -INFINITY; lrun[r] = 0.f; }
      loadQ(qtB * 64);
    }
    __syncthreads();
    cur ^= 1;
  }
#pragma unroll
  for (int r = 0; r < 4; ++r) {
    float rl = 1.0f / lrun[r];
    int row = qtB * 64 + wid * 16 + lk * 4 + r;
    size_t base = ((size_t)(b * S + row)) * 2048 + h * 128;
#pragma unroll
    for (int n8 = 0; n8 < 8; ++n8)
      O[base + n8 * 16 + lr] = (bf16)(o[n8][r] * rl);
  }
}

// ---------------- launch ----------------

extern "C" void kernel_launch(void* const* d_in, const int* in_sizes, int n_in,
                              void* d_out, int out_size, void* d_ws, size_t ws_size,
                              hipStream_t stream) {
  const float* x  = (const float*)d_in[0];
  const float* Wq = (const float*)d_in[1];
  const float* bq = (const float*)d_in[2];
  const float* Wk = (const float*)d_in[3];
  const float* bk = (const float*)d_in[4];
  const float* Wv = (const float*)d_in[5];
  const float* bv = (const float*)d_in[6];
  const float* Wo = (const float*)d_in[7];
  const float* bo = (const float*)d_in[8];

  char* ws = (char*)d_ws;
  bf16* xb     = (bf16*)(ws);                  // 16 MB (x bf16; reused as attn_out after GEMM1)
  bf16* wqkv   = (bf16*)(ws + 16777216);       // 24 MB (Wq|Wk|Wv bf16, 6144x2048)
  bf16* wob    = (bf16*)(ws + 41943040);       // 8 MB
  bf16* qkv    = (bf16*)(ws + 50331648);       // 50.3 MB, live until attn done
  bf16* kr     = (bf16*)(ws + 100663296);      // 16 MB (RoPE'd K)
  bf16* vt     = (bf16*)(ws + 117440512);      // 16 MB (V^T)
  float* biasq = (float*)(ws + 134217728);     // 24 KB
  float* cost  = (float*)(ws + 134242304);     // 512 KB
  float* sint  = (float*)(ws + 134766592);     // 512 KB (ws end: 135290880)
  bf16* attn_out = xb;                         // alias: x_bf16 dead after GEMM1

  prep_kernel<<<25112, 256, 0, stream>>>(x, Wq, Wk, Wv, Wo, bq, bk, bv,
                                         xb, wqkv, wob, biasq, cost, sint);
  // qkv = x @ [Wq|Wk|Wv]^T + bias  (4096 x 6144 x 2048): 1024 blocks, 2/CU -> 2 rounds
  gemm4w_kernel<192, true><<<1024, 256, 0, stream>>>(xb, wqkv, biasq, qkv, 4096, 6144, 2048);
  rope_tv_kernel<<<6144, 256, 0, stream>>>(qkv, cost, sint, kr, vt);
  attn_kernel<<<512, 256, 0, stream>>>(qkv, kr, vt, cost, sint, attn_out, 2048);
  // out = attn @ Wo^T + bo  (4096 x 2048 x 2048), fp32 out: 512 blocks, 2/CU -> 1 round
  gemm4w_kernel<128, false><<<512, 256, 0, stream>>>(attn_out, wob, bo, (float*)d_out, 4096, 2048, 2048);
}

// Round 18
// 286.539 us; speedup vs baseline: 1.0068x; 1.0068x over previous
//
#include <hip/hip_runtime.h>
#include <math.h>

typedef __bf16 bf16;
typedef __attribute__((ext_vector_type(2))) __bf16 bf16x2;
typedef __attribute__((ext_vector_type(4))) __bf16 bf16x4;
typedef __attribute__((ext_vector_type(8))) __bf16 bf16x8;
typedef __attribute__((ext_vector_type(4))) float f32x4;
typedef __attribute__((ext_vector_type(16))) float f32x16;

#define GLD16(g, l) __builtin_amdgcn_global_load_lds( \
    (const __attribute__((address_space(1))) void*)(g), \
    (__attribute__((address_space(3))) void*)(l), 16, 0, 0)

template<int N> __device__ __forceinline__ void wait_vm() {
  static_assert(N == 0 || N == 4 || N == 6, "");
  if constexpr (N == 0) asm volatile("s_waitcnt vmcnt(0)" ::: "memory");
  else if constexpr (N == 4) asm volatile("s_waitcnt vmcnt(4)" ::: "memory");
  else asm volatile("s_waitcnt vmcnt(6)" ::: "memory");
}

// ---------------- fused prologue: casts + bias concat + rope table ----------------
__global__ void prep_kernel(const float* __restrict__ x,
                            const float* __restrict__ Wq, const float* __restrict__ Wk,
                            const float* __restrict__ Wv, const float* __restrict__ Wo,
                            const float* __restrict__ bq, const float* __restrict__ bk,
                            const float* __restrict__ bv,
                            bf16* __restrict__ xb, bf16* __restrict__ wqkv, bf16* __restrict__ wob,
                            float* __restrict__ biasq, float* __restrict__ cost, float* __restrict__ sint) {
  const int bid = blockIdx.x, t = threadIdx.x;
  if (bid < 24576) {
    const float* src;
    bf16* dst;
    int i;
    if (bid < 8192)       { src = x;  dst = xb;                    i = bid * 256 + t; }
    else if (bid < 12288) { src = Wq; dst = wqkv;                  i = (bid - 8192) * 256 + t; }
    else if (bid < 16384) { src = Wk; dst = wqkv + 2048 * 2048;    i = (bid - 12288) * 256 + t; }
    else if (bid < 20480) { src = Wv; dst = wqkv + 2 * 2048 * 2048; i = (bid - 16384) * 256 + t; }
    else                  { src = Wo; dst = wob;                   i = (bid - 20480) * 256 + t; }
    float4 f = ((const float4*)src)[i];
    bf16x4 o;
    o[0] = (bf16)f.x; o[1] = (bf16)f.y; o[2] = (bf16)f.z; o[3] = (bf16)f.w;
    ((bf16x4*)dst)[i] = o;
  } else if (bid < 25088) {
    int i = (bid - 24576) * 256 + t;  // S*64
    int s = i >> 6, d = i & 63;
    float inv = powf(10000.0f, -(float)d / 64.0f);
    float ang = (float)s * inv;
    cost[i] = cosf(ang);
    sint[i] = sinf(ang);
  } else {
    int i = (bid - 25088) * 256 + t;  // 6144
    biasq[i] = (i < 2048) ? bq[i] : (i < 4096 ? bk[i - 2048] : bv[i - 4096]);
  }
}

// ---------------- fused RoPE-K + V-transpose (region-switched) ----------------
__global__ void rope_tv_kernel(const bf16* __restrict__ qkv,
                               const float* __restrict__ cost, const float* __restrict__ sint,
                               bf16* __restrict__ kr, bf16* __restrict__ vt) {
  __shared__ bf16 Vl[64 * 72];
  const int t = threadIdx.x;
  if (blockIdx.x < 4096) {
    int idx = blockIdx.x * 256 + t;  // (b,s,h,dp), dp<16 -> d0=dp*4
    int dp = idx & 15;
    int h = (idx >> 4) & 15;
    int s = (idx >> 8) & 2047;
    int b = idx >> 19;
    int d0 = dp * 4;
    const bf16* row = qkv + ((size_t)(b * 2048 + s) * 6144) + 2048 + h * 128;
    bf16x4 klo = *(const bf16x4*)&row[d0];
    bf16x4 khi = *(const bf16x4*)&row[d0 + 64];
    float4 c4 = *(const float4*)&cost[(s << 6) + d0];
    float4 s4 = *(const float4*)&sint[(s << 6) + d0];
    float cf[4] = {c4.x, c4.y, c4.z, c4.w};
    float sf[4] = {s4.x, s4.y, s4.z, s4.w};
    bf16x4 olo, ohi;
#pragma unroll
    for (int j = 0; j < 4; ++j) {
      float kl = (float)klo[j], kh = (float)khi[j];
      olo[j] = (bf16)(kl * cf[j] - kh * sf[j]);
      ohi[j] = (bf16)(kh * cf[j] + kl * sf[j]);
    }
    bf16* orow = kr + (((size_t)(b * 16 + h) * 2048 + s) * 128);
    *(bf16x4*)&orow[d0] = olo;
    *(bf16x4*)&orow[d0 + 64] = ohi;
  } else {
    int vbid = blockIdx.x - 4096;   // 2048 blocks
    const int dt = vbid & 1, st = (vbid >> 1) & 31, bh = vbid >> 6;
    const int b = bh >> 4, h = bh & 15;
    const bf16* src = qkv + ((size_t)(b * 2048 + st * 64) * 6144) + 4096 + h * 128 + dt * 64;
    bf16* dst = vt + ((size_t)bh * 128 + dt * 64) * 2048 + st * 64;
#pragma unroll
    for (int i = 0; i < 2; ++i) {
      int c = i * 256 + t;
      int r = c >> 3, c0 = (c & 7) * 8;
      *(bf16x8*)&Vl[r * 72 + c0] = *(const bf16x8*)&src[(size_t)r * 6144 + c0];
    }
    __syncthreads();
#pragma unroll
    for (int i = 0; i < 2; ++i) {
      int c = i * 256 + t;
      int r = c >> 3, c0 = (c & 7) * 8;
      bf16x8 v;
#pragma unroll
      for (int j = 0; j < 8; ++j) v[j] = Vl[(c0 + j) * 72 + r];
      *(bf16x8*)&dst[(size_t)r * 2048 + c0] = v;
    }
  }
}

// ---------------- GEMM 128xBN kk-split 2-phase, 4-wave, 2 blocks/CU, 32x32x16 MFMA ----------------
// Same staging/sync/ledger as the proven R9 kernel; only fragment indexing + epilogue
// changed to the 32x32x16 shape (half the MFMA instructions, higher pipe ceiling m119).
// A/B lane layout: row(col) = lane&31, k = (lane>>5)*8 + j. C/D: col = lane&31,
// row = (reg&3) + 8*(reg>>2) + 4*(lane>>5) (guide m74/m101).
template<int BN, bool OUT_BF16>
__global__ __launch_bounds__(256, 2)
void gemm4w_kernel(const bf16* __restrict__ A, const bf16* __restrict__ B,
                   const float* __restrict__ bias, void* __restrict__ Cp,
                   int M, int N, int K) {
  constexpr int NB = BN / 64;    // B LDS units (64x64)
  constexpr int NTW = BN / 64;   // 32-col tiles per wave (= BN/2/32)
  __shared__ bf16 Al[2][128 * 64];
  __shared__ bf16 Bl[2][NB][64 * 64];
  const int t = threadIdx.x;
  const int wid = t >> 6, lane = t & 63;
  const int wr = wid >> 1, wc = wid & 1;
  const int l31 = lane & 31, l5 = lane >> 5;
  const int flat = (int)blockIdx.x;
  const int xcd = flat & 7, r0 = flat >> 3;
  const int tm = xcd * 4 + (r0 & 3);
  const int tn = r0 >> 2;
  const bf16* Ab = A + (size_t)tm * 128 * K;
  const bf16* Bb = B + (size_t)tn * BN * K;
  const int NT = K >> 6;

  auto stageA = [&](int bp, int h, int kt) {   // one 64x64 half, 2 insts/thread
#pragma unroll
    for (int q = 0; q < 2; ++q) {
      int e = q * 256 + t;
      int r = e >> 3, c = e & 7;
      GLD16(Ab + (size_t)(h * 64 + r) * K + kt * 64 + ((c ^ (r & 7)) << 3),
            &Al[bp][h * 4096 + e * 8]);
    }
  };
  auto stageB = [&](int bp, int unit, int kt) {  // one 64x64 unit, 2 insts/thread
#pragma unroll
    for (int q = 0; q < 2; ++q) {
      int e = q * 256 + t;
      int r = e >> 3, c = e & 7;
      GLD16(Bb + (size_t)(unit * 64 + r) * K + kt * 64 + ((c ^ (r & 7)) << 3),
            &Bl[bp][unit][e * 8]);
    }
  };
  // 32x32x16 fragments: ks = 16-k step (0..3); chunk = ks*2 + (lane>>5)
  auto readA = [&](int bp, int mt, int ks) -> bf16x8 {
    int row = wr * 64 + mt * 32 + l31;
    return *(const bf16x8*)&Al[bp][row * 64 + (((ks * 2 + l5) ^ (row & 7)) << 3)];
  };
  auto readB = [&](int bp, int nt, int ks) -> bf16x8 {
    int rb = wc * (BN / 2) + nt * 32 + l31;
    int r = rb & 63;
    return *(const bf16x8*)&Bl[bp][rb >> 6][r * 64 + (((ks * 2 + l5) ^ (r & 7)) << 3)];
  };

  f32x16 acc[2][NTW] = {};

  // prologue: B(0), A(0), B(1); leave B(1) (2*NB insts) in flight
#pragma unroll
  for (int un = 0; un < NB; ++un) stageB(0, un, 0);
  stageA(0, 0, 0); stageA(0, 1, 0);
  if (NT > 1) {
#pragma unroll
    for (int un = 0; un < NB; ++un) stageB(1, un, 1);
    wait_vm<2 * NB>();
  } else {
    wait_vm<0>();
  }
  __builtin_amdgcn_s_barrier();
  __builtin_amdgcn_sched_barrier(0);

  for (int u = 0; u < NT; ++u) {
    const int p = u & 1;
    // ---- phase 0 head: all B frags (4 ks) + A(ks 0,1); stage A(u+1) ----
    bf16x8 bfr[NTW][4], afr[2][2];
#pragma unroll
    for (int n = 0; n < NTW; ++n)
#pragma unroll
      for (int ks = 0; ks < 4; ++ks) bfr[n][ks] = readB(p, n, ks);
#pragma unroll
    for (int mt = 0; mt < 2; ++mt)
#pragma unroll
      for (int ks = 0; ks < 2; ++ks) afr[mt][ks] = readA(p, mt, ks);
    if (u + 1 < NT) { stageA(p ^ 1, 0, u + 1); stageA(p ^ 1, 1, u + 1); }
    __builtin_amdgcn_s_barrier();
    asm volatile("s_waitcnt lgkmcnt(0)" ::: "memory");
    __builtin_amdgcn_sched_barrier(0);
    __builtin_amdgcn_s_setprio(1);
#pragma unroll
    for (int ks = 0; ks < 2; ++ks)
#pragma unroll
      for (int mt = 0; mt < 2; ++mt)
#pragma unroll
        for (int n = 0; n < NTW; ++n)
          acc[mt][n] = __builtin_amdgcn_mfma_f32_32x32x16_bf16(afr[mt][ks], bfr[n][ks], acc[mt][n], 0, 0, 0);
    __builtin_amdgcn_s_setprio(0);
    __builtin_amdgcn_sched_barrier(0);
    // ---- phase 1 head: A(ks 2,3); stage B(u+2) (Bl[p] reads drained at ph0 lgkm) ----
#pragma unroll
    for (int mt = 0; mt < 2; ++mt)
#pragma unroll
      for (int ks = 0; ks < 2; ++ks) afr[mt][ks] = readA(p, mt, ks + 2);
    if (u + 2 < NT) {
#pragma unroll
      for (int un = 0; un < NB; ++un) stageB(p, un, u + 2);
    }
    __builtin_amdgcn_s_barrier();
    asm volatile("s_waitcnt lgkmcnt(0)" ::: "memory");
    __builtin_amdgcn_sched_barrier(0);
    __builtin_amdgcn_s_setprio(1);
#pragma unroll
    for (int ks = 0; ks < 2; ++ks)
#pragma unroll
      for (int mt = 0; mt < 2; ++mt)
#pragma unroll
        for (int n = 0; n < NTW; ++n)
          acc[mt][n] = __builtin_amdgcn_mfma_f32_32x32x16_bf16(afr[mt][ks], bfr[n][ks + 2], acc[mt][n], 0, 0, 0);
    __builtin_amdgcn_s_setprio(0);
    __builtin_amdgcn_sched_barrier(0);
    if (u + 2 < NT) { wait_vm<2 * NB>(); }
    else            { wait_vm<0>(); }
    __builtin_amdgcn_s_barrier();
    __builtin_amdgcn_sched_barrier(0);
  }

  const int rbase = tm * 128 + wr * 64, cbase = tn * BN + wc * (BN / 2);
#pragma unroll
  for (int n = 0; n < NTW; ++n) {
    int col = cbase + n * 32 + l31;
    float bvl = bias[col];
#pragma unroll
    for (int mt = 0; mt < 2; ++mt) {
#pragma unroll
      for (int reg = 0; reg < 16; ++reg) {
        int row = rbase + mt * 32 + (reg & 3) + 8 * (reg >> 2) + 4 * l5;
        float v = acc[mt][n][reg] + bvl;
        if (OUT_BF16) ((bf16*)Cp)[(size_t)row * N + col] = (bf16)v;
        else          ((float*)Cp)[(size_t)row * N + col] = v;
      }
    }
  }
}

// ---------------- causal flash attention (R12 proven: double-buffered + fast-path softmax) ----------------
// Q read directly from qkv with RoPE and scale*log2(e) folded; K from kr; V^T from vt.
// Double-buffered K/V prefetch (stage t+1 during compute of t). Fast-path softmax:
// per-thread max + __any ballot; cross-lane max tree + rescale only when running max
// grows >6 (log2 domain); row-sum shfl tree deferred until after PV MFMAs are issued.
// Launch bounds (256,3): proven 112 VGPR, no spill. XCD map: xcd owns bh {4x..4x+3}.
__global__ __launch_bounds__(256, 3)
void attn_kernel(const bf16* __restrict__ qkv, const bf16* __restrict__ Kc,
                 const bf16* __restrict__ Vtg, const float* __restrict__ cost,
                 const float* __restrict__ sint, bf16* __restrict__ O, int S) {
  __shared__ bf16 Kl[2][64 * 128];  // [kv][d], 16B chunks XOR-swizzled by kv&7
  __shared__ bf16 Vt[2][128 * 64];  // [d][kv], 16B chunks XOR-swizzled by d&7
  __shared__ bf16 Pl[4][16 * 64];   // per-wave P, rows XOR-swizzled by row&7
  const int t = threadIdx.x, wid = t >> 6, lane = t & 63;
  const int lr = lane & 15, lk = lane >> 4;
  const int flat = (int)blockIdx.x;
  const int xcd = flat & 7, kk2 = flat >> 3;     // kk2 0..63
  const int bh = xcd * 4 + (kk2 >> 4);           // 4 bh per XCD
  const int b = bh >> 4, h = bh & 15;
  const int NQ = S >> 6;
  const int qtA = kk2 & 15, qtB = NQ - 1 - qtA;
  const int ntA = qtA + 1, ntB = qtB + 1, total = ntA + ntB;  // == NQ+1 for all blocks
  const bf16* Kb = Kc + (size_t)bh * S * 128;
  const bf16* Vb = Vtg + (size_t)bh * 128 * S;
  const float SCL2 = 0.12752040147f;  // (1/sqrt(128)) * log2(e) -> log2-domain logits

  bf16x8 qf[4];
  auto loadQ = [&](int q0) {
    int qrow = q0 + wid * 16 + lr;
    const bf16* qp = qkv + (size_t)(b * 2048 + qrow) * 6144 + h * 128;
    bf16x8 raw[4];
#pragma unroll
    for (int kb = 0; kb < 4; ++kb) raw[kb] = *(const bf16x8*)&qp[kb * 32 + lk * 8];
#pragma unroll
    for (int kb = 0; kb < 4; ++kb) {
      const float* cb = cost + (qrow << 6) + ((kb & 1) << 5) + lk * 8;
      const float* sb = sint + (qrow << 6) + ((kb & 1) << 5) + lk * 8;
#pragma unroll
      for (int j = 0; j < 8; ++j) {
        float qv = (float)raw[kb][j];
        float qo = (float)raw[kb ^ 2][j];
        float rot = (kb < 2) ? -qo : qo;   // d<64 <=> kb<2
        qf[kb][j] = (bf16)((qv * cb[j] + rot * sb[j]) * SCL2);
      }
    }
  };
  auto stage = [&](int buf, int kv0) {
#pragma unroll
    for (int c = 0; c < 4; ++c) {
      int fc = c * 256 + t;
      int kvr = fc >> 4, cc = fc & 15;
      GLD16(Kb + (size_t)(kv0 + kvr) * 128 + (cc ^ (kvr & 7)) * 8, &Kl[buf][fc * 8]);
      int dr = fc >> 3, c2 = fc & 7;
      GLD16(Vb + (size_t)dr * S + kv0 + (c2 ^ (dr & 7)) * 8, &Vt[buf][fc * 8]);
    }
  };

  f32x4 o[8] = {};
  float mrun[4], lrun[4];
#pragma unroll
  for (int r = 0; r < 4; ++r) { mrun[r] = -INFINITY; lrun[r] = 0.f; }

  loadQ(qtA * 64);
  stage(0, 0);
  __syncthreads();  // tile 0 resident
  int cur = 0;
  for (int ti = 0; ti < total; ++ti) {
    if (ti + 1 < total) {
      int tn = ti + 1;
      stage(cur ^ 1, ((tn < ntA) ? tn : tn - ntA) * 64);
    }
    __builtin_amdgcn_sched_barrier(0);
    const bool isA = ti < ntA;
    const int tt = isA ? ti : ti - ntA;
    const int nt = isA ? ntA : ntB;
    const int q0 = (isA ? qtA : qtB) * 64;
    const int kv0 = tt * 64;
    f32x4 sa[4];
    __builtin_amdgcn_s_setprio(1);
#pragma unroll
    for (int n = 0; n < 4; ++n) {
      sa[n] = (f32x4){0.f, 0.f, 0.f, 0.f};
      int kvl = n * 16 + lr;
#pragma unroll
      for (int kb = 0; kb < 4; ++kb) {
        bf16x8 kf = *(const bf16x8*)&Kl[cur][kvl * 128 + (((kb << 2) | lk) ^ (kvl & 7)) * 8];
        sa[n] = __builtin_amdgcn_mfma_f32_16x16x32_bf16(qf[kb], kf, sa[n], 0, 0, 0);
      }
    }
    __builtin_amdgcn_s_setprio(0);
    // ---- fast-path softmax (log2 domain) ----
    float p[4][4];
    float tmax[4] = {-INFINITY, -INFINITY, -INFINITY, -INFINITY};
    const bool lastTile = (tt == nt - 1);
#pragma unroll
    for (int n = 0; n < 4; ++n)
#pragma unroll
      for (int r = 0; r < 4; ++r) {
        float s = sa[n][r];
        if (lastTile) {
          int kvg = kv0 + n * 16 + lr;
          int qg = q0 + wid * 16 + lk * 4 + r;
          if (kvg > qg) s = -INFINITY;
        }
        p[n][r] = s;
        tmax[r] = fmaxf(tmax[r], s);   // per-thread only (4 values)
      }
    bool need = false;
#pragma unroll
    for (int r = 0; r < 4; ++r) need = need || (tmax[r] > mrun[r] + 6.0f);
    if (__any(need)) {   // slow path: full cross-lane max + rescale (rare)
#pragma unroll
      for (int r = 0; r < 4; ++r) {
#pragma unroll
        for (int off = 1; off < 16; off <<= 1)
          tmax[r] = fmaxf(tmax[r], __shfl_xor(tmax[r], off));
        float mnew = fmaxf(mrun[r], tmax[r]);
        float alpha = exp2f(mrun[r] - mnew);
        mrun[r] = mnew;
        lrun[r] *= alpha;
#pragma unroll
        for (int n8 = 0; n8 < 8; ++n8) o[n8][r] *= alpha;
      }
    }
#pragma unroll
    for (int n = 0; n < 4; ++n)
#pragma unroll
      for (int r = 0; r < 4; ++r)
        p[n][r] = exp2f(p[n][r] - mrun[r]);   // bounded by 2^6
    // write P and launch PV immediately (sum tree deferred)
#pragma unroll
    for (int n = 0; n < 4; ++n)
#pragma unroll
      for (int r = 0; r < 4; ++r) {
        int row = lk * 4 + r, col = n * 16 + lr;
        Pl[wid][(row * 64 + col) ^ ((row & 7) << 3)] = (bf16)p[n][r];
      }
    __builtin_amdgcn_s_setprio(1);
#pragma unroll
    for (int kb2 = 0; kb2 < 2; ++kb2) {
      bf16x8 pf = *(const bf16x8*)&Pl[wid][(lr * 64 + kb2 * 32 + lk * 8) ^ ((lr & 7) << 3)];
#pragma unroll
      for (int n8 = 0; n8 < 8; ++n8) {
        int dcol = n8 * 16 + lr;
        bf16x8 vf = *(const bf16x8*)&Vt[cur][(dcol * 64 + kb2 * 32 + lk * 8) ^ ((dcol & 7) << 3)];
        o[n8] = __builtin_amdgcn_mfma_f32_16x16x32_bf16(pf, vf, o[n8], 0, 0, 0);
      }
    }
    __builtin_amdgcn_s_setprio(0);
    // ---- deferred row-sum (overlaps PV on the DS/VALU pipes) ----
    {
      float rsum[4];
#pragma unroll
      for (int r = 0; r < 4; ++r) {
        rsum[r] = (p[0][r] + p[1][r]) + (p[2][r] + p[3][r]);
#pragma unroll
        for (int off = 1; off < 16; off <<= 1)
          rsum[r] += __shfl_xor(rsum[r], off);
        lrun[r] += rsum[r];
      }
    }
    if (ti == ntA - 1) {
#pragma unroll
      for (int r = 0; r < 4; ++r) {
        float rl = 1.0f / lrun[r];
        int row = qtA * 64 + wid * 16 + lk * 4 + r;
        size_t base = ((size_t)(b * S + row)) * 2048 + h * 128;
#pragma unroll
        for (int n8 = 0; n8 < 8; ++n8)
          O[base + n8 * 16 + lr] = (bf16)(o[n8][r] * rl);
      }
#pragma unroll
      for (int n8 = 0; n8 < 8; ++n8) o[n8] = (f32x4){0.f, 0.f, 0.f, 0.f};
#pragma unroll
      for (int r = 0; r < 4; ++r) { mrun[r] = -INFINITY; lrun[r] = 0.f; }
      loadQ(qtB * 64);
    }
    __syncthreads();
    cur ^= 1;
  }
#pragma unroll
  for (int r = 0; r < 4; ++r) {
    float rl = 1.0f / lrun[r];
    int row = qtB * 64 + wid * 16 + lk * 4 + r;
    size_t base = ((size_t)(b * S + row)) * 2048 + h * 128;
#pragma unroll
    for (int n8 = 0; n8 < 8; ++n8)
      O[base + n8 * 16 + lr] = (bf16)(o[n8][r] * rl);
  }
}

// ---------------- launch ----------------

extern "C" void kernel_launch(void* const* d_in, const int* in_sizes, int n_in,
                              void* d_out, int out_size, void* d_ws, size_t ws_size,
                              hipStream_t stream) {
  const float* x  = (const float*)d_in[0];
  const float* Wq = (const float*)d_in[1];
  const float* bq = (const float*)d_in[2];
  const float* Wk = (const float*)d_in[3];
  const float* bk = (const float*)d_in[4];
  const float* Wv = (const float*)d_in[5];
  const float* bv = (const float*)d_in[6];
  const float* Wo = (const float*)d_in[7];
  const float* bo = (const float*)d_in[8];

  char* ws = (char*)d_ws;
  bf16* xb     = (bf16*)(ws);                  // 16 MB (x bf16; reused as attn_out after GEMM1)
  bf16* wqkv   = (bf16*)(ws + 16777216);       // 24 MB (Wq|Wk|Wv bf16, 6144x2048)
  bf16* wob    = (bf16*)(ws + 41943040);       // 8 MB
  bf16* qkv    = (bf16*)(ws + 50331648);       // 50.3 MB, live until attn done
  bf16* kr     = (bf16*)(ws + 100663296);      // 16 MB (RoPE'd K)
  bf16* vt     = (bf16*)(ws + 117440512);      // 16 MB (V^T)
  float* biasq = (float*)(ws + 134217728);     // 24 KB
  float* cost  = (float*)(ws + 134242304);     // 512 KB
  float* sint  = (float*)(ws + 134766592);     // 512 KB (ws end: 135290880)
  bf16* attn_out = xb;                         // alias: x_bf16 dead after GEMM1

  prep_kernel<<<25112, 256, 0, stream>>>(x, Wq, Wk, Wv, Wo, bq, bk, bv,
                                         xb, wqkv, wob, biasq, cost, sint);
  // qkv = x @ [Wq|Wk|Wv]^T + bias  (4096 x 6144 x 2048): 1024 blocks, 2/CU -> 2 rounds
  gemm4w_kernel<192, true><<<1024, 256, 0, stream>>>(xb, wqkv, biasq, qkv, 4096, 6144, 2048);
  rope_tv_kernel<<<6144, 256, 0, stream>>>(qkv, cost, sint, kr, vt);
  attn_kernel<<<512, 256, 0, stream>>>(qkv, kr, vt, cost, sint, attn_out, 2048);
  // out = attn @ Wo^T + bo  (4096 x 2048 x 2048), fp32 out: 512 blocks, 2/CU -> 1 round
  gemm4w_kernel<128, false><<<512, 256, 0, stream>>>(attn_out, wob, bo, (float*)d_out, 4096, 2048, 2048);
}

// Round 19
// 267.902 us; speedup vs baseline: 1.0768x; 1.0696x over previous
//
#include <hip/hip_runtime.h>
#include <math.h>

typedef __bf16 bf16;
typedef __attribute__((ext_vector_type(2))) __bf16 bf16x2;
typedef __attribute__((ext_vector_type(4))) __bf16 bf16x4;
typedef __attribute__((ext_vector_type(8))) __bf16 bf16x8;
typedef __attribute__((ext_vector_type(4))) float f32x4;

#define GLD16(g, l) __builtin_amdgcn_global_load_lds( \
    (const __attribute__((address_space(1))) void*)(g), \
    (__attribute__((address_space(3))) void*)(l), 16, 0, 0)

template<int N> __device__ __forceinline__ void wait_vm() {
  static_assert(N == 0 || N == 4 || N == 6, "");
  if constexpr (N == 0) asm volatile("s_waitcnt vmcnt(0)" ::: "memory");
  else if constexpr (N == 4) asm volatile("s_waitcnt vmcnt(4)" ::: "memory");
  else asm volatile("s_waitcnt vmcnt(6)" ::: "memory");
}

// ---------------- fused prologue: casts + bias concat + rope table ----------------
__global__ void prep_kernel(const float* __restrict__ x,
                            const float* __restrict__ Wq, const float* __restrict__ Wk,
                            const float* __restrict__ Wv, const float* __restrict__ Wo,
                            const float* __restrict__ bq, const float* __restrict__ bk,
                            const float* __restrict__ bv,
                            bf16* __restrict__ xb, bf16* __restrict__ wqkv, bf16* __restrict__ wob,
                            float* __restrict__ biasq, float* __restrict__ cost, float* __restrict__ sint) {
  const int bid = blockIdx.x, t = threadIdx.x;
  if (bid < 24576) {
    const float* src;
    bf16* dst;
    int i;
    if (bid < 8192)       { src = x;  dst = xb;                    i = bid * 256 + t; }
    else if (bid < 12288) { src = Wq; dst = wqkv;                  i = (bid - 8192) * 256 + t; }
    else if (bid < 16384) { src = Wk; dst = wqkv + 2048 * 2048;    i = (bid - 12288) * 256 + t; }
    else if (bid < 20480) { src = Wv; dst = wqkv + 2 * 2048 * 2048; i = (bid - 16384) * 256 + t; }
    else                  { src = Wo; dst = wob;                   i = (bid - 20480) * 256 + t; }
    float4 f = ((const float4*)src)[i];
    bf16x4 o;
    o[0] = (bf16)f.x; o[1] = (bf16)f.y; o[2] = (bf16)f.z; o[3] = (bf16)f.w;
    ((bf16x4*)dst)[i] = o;
  } else if (bid < 25088) {
    int i = (bid - 24576) * 256 + t;  // S*64
    int s = i >> 6, d = i & 63;
    float inv = powf(10000.0f, -(float)d / 64.0f);
    float ang = (float)s * inv;
    cost[i] = cosf(ang);
    sint[i] = sinf(ang);
  } else {
    int i = (bid - 25088) * 256 + t;  // 6144
    biasq[i] = (i < 2048) ? bq[i] : (i < 4096 ? bk[i - 2048] : bv[i - 4096]);
  }
}

// ---------------- fused RoPE-K + V-transpose (region-switched) ----------------
__global__ void rope_tv_kernel(const bf16* __restrict__ qkv,
                               const float* __restrict__ cost, const float* __restrict__ sint,
                               bf16* __restrict__ kr, bf16* __restrict__ vt) {
  __shared__ bf16 Vl[64 * 72];
  const int t = threadIdx.x;
  if (blockIdx.x < 4096) {
    int idx = blockIdx.x * 256 + t;  // (b,s,h,dp), dp<16 -> d0=dp*4
    int dp = idx & 15;
    int h = (idx >> 4) & 15;
    int s = (idx >> 8) & 2047;
    int b = idx >> 19;
    int d0 = dp * 4;
    const bf16* row = qkv + ((size_t)(b * 2048 + s) * 6144) + 2048 + h * 128;
    bf16x4 klo = *(const bf16x4*)&row[d0];
    bf16x4 khi = *(const bf16x4*)&row[d0 + 64];
    float4 c4 = *(const float4*)&cost[(s << 6) + d0];
    float4 s4 = *(const float4*)&sint[(s << 6) + d0];
    float cf[4] = {c4.x, c4.y, c4.z, c4.w};
    float sf[4] = {s4.x, s4.y, s4.z, s4.w};
    bf16x4 olo, ohi;
#pragma unroll
    for (int j = 0; j < 4; ++j) {
      float kl = (float)klo[j], kh = (float)khi[j];
      olo[j] = (bf16)(kl * cf[j] - kh * sf[j]);
      ohi[j] = (bf16)(kh * cf[j] + kl * sf[j]);
    }
    bf16* orow = kr + (((size_t)(b * 16 + h) * 2048 + s) * 128);
    *(bf16x4*)&orow[d0] = olo;
    *(bf16x4*)&orow[d0 + 64] = ohi;
  } else {
    int vbid = blockIdx.x - 4096;   // 2048 blocks
    const int dt = vbid & 1, st = (vbid >> 1) & 31, bh = vbid >> 6;
    const int b = bh >> 4, h = bh & 15;
    const bf16* src = qkv + ((size_t)(b * 2048 + st * 64) * 6144) + 4096 + h * 128 + dt * 64;
    bf16* dst = vt + ((size_t)bh * 128 + dt * 64) * 2048 + st * 64;
#pragma unroll
    for (int i = 0; i < 2; ++i) {
      int c = i * 256 + t;
      int r = c >> 3, c0 = (c & 7) * 8;
      *(bf16x8*)&Vl[r * 72 + c0] = *(const bf16x8*)&src[(size_t)r * 6144 + c0];
    }
    __syncthreads();
#pragma unroll
    for (int i = 0; i < 2; ++i) {
      int c = i * 256 + t;
      int r = c >> 3, c0 = (c & 7) * 8;
      bf16x8 v;
#pragma unroll
      for (int j = 0; j < 8; ++j) v[j] = Vl[(c0 + j) * 72 + r];
      *(bf16x8*)&dst[(size_t)r * 2048 + c0] = v;
    }
  }
}

// ---------------- GEMM 128xBN kk-split 2-phase, 4-wave, 2 blocks/CU ----------------
// 16x16x32 MFMA (conflict-free fragment reads in [row][64] LDS; 32x32 shape is an
// unavoidable 4-way bank conflict here — R18). Proven R9 staging/sync/ledger.
template<int BN, bool OUT_BF16>
__global__ __launch_bounds__(256, 2)
void gemm4w_kernel(const bf16* __restrict__ A, const bf16* __restrict__ B,
                   const float* __restrict__ bias, void* __restrict__ Cp,
                   int M, int N, int K) {
  constexpr int NB = BN / 64;   // B LDS units
  constexpr int NR = BN / 32;   // n-tiles per wave
  __shared__ bf16 Al[2][128 * 64];
  __shared__ bf16 Bl[2][NB][64 * 64];
  const int t = threadIdx.x;
  const int wid = t >> 6, lane = t & 63;
  const int wr = wid >> 1, wc = wid & 1;
  const int lr = lane & 15, lk = lane >> 4;
  const int flat = (int)blockIdx.x;
  const int xcd = flat & 7, r0 = flat >> 3;
  const int tm = xcd * 4 + (r0 & 3);
  const int tn = r0 >> 2;
  const bf16* Ab = A + (size_t)tm * 128 * K;
  const bf16* Bb = B + (size_t)tn * BN * K;
  const int NT = K >> 6;

  auto stageA = [&](int bp, int h, int kt) {   // one 64x64 half, 2 insts/thread
#pragma unroll
    for (int q = 0; q < 2; ++q) {
      int e = q * 256 + t;
      int r = e >> 3, c = e & 7;
      GLD16(Ab + (size_t)(h * 64 + r) * K + kt * 64 + ((c ^ (r & 7)) << 3),
            &Al[bp][h * 4096 + e * 8]);
    }
  };
  auto stageB = [&](int bp, int unit, int kt) {  // one 64x64 unit, 2 insts/thread
#pragma unroll
    for (int q = 0; q < 2; ++q) {
      int e = q * 256 + t;
      int r = e >> 3, c = e & 7;
      GLD16(Bb + (size_t)(unit * 64 + r) * K + kt * 64 + ((c ^ (r & 7)) << 3),
            &Bl[bp][unit][e * 8]);
    }
  };
  auto readA = [&](int bp, int m, int kk) -> bf16x8 {
    int row = wr * 64 + m * 16 + lr;
    return *(const bf16x8*)&Al[bp][row * 64 + ((((kk << 2) | lk) ^ (row & 7)) << 3)];
  };
  auto readB = [&](int bp, int n, int kk) -> bf16x8 {
    int rb = wc * (NR * 16) + n * 16 + lr;
    return *(const bf16x8*)&Bl[bp][rb >> 6][(rb & 63) * 64 + ((((kk << 2) | lk) ^ (rb & 7)) << 3)];
  };

  f32x4 acc[4][NR] = {};

  // prologue: B(0), A(0), B(1); leave B(1) (2*NB insts) in flight
#pragma unroll
  for (int un = 0; un < NB; ++un) stageB(0, un, 0);
  stageA(0, 0, 0); stageA(0, 1, 0);
  if (NT > 1) {
#pragma unroll
    for (int un = 0; un < NB; ++un) stageB(1, un, 1);
    wait_vm<2 * NB>();
  } else {
    wait_vm<0>();
  }
  __builtin_amdgcn_s_barrier();
  __builtin_amdgcn_sched_barrier(0);

  for (int u = 0; u < NT; ++u) {
    const int p = u & 1;
    // ---- phase 0 head: all B frags + A(kk=0); stage A(u+1) ----
    bf16x8 bfr[NR][2], afr[4];
#pragma unroll
    for (int n = 0; n < NR; ++n)
#pragma unroll
      for (int kk = 0; kk < 2; ++kk) bfr[n][kk] = readB(p, n, kk);
#pragma unroll
    for (int m = 0; m < 4; ++m) afr[m] = readA(p, m, 0);
    if (u + 1 < NT) { stageA(p ^ 1, 0, u + 1); stageA(p ^ 1, 1, u + 1); }
    __builtin_amdgcn_s_barrier();
    asm volatile("s_waitcnt lgkmcnt(0)" ::: "memory");
    __builtin_amdgcn_sched_barrier(0);
    __builtin_amdgcn_s_setprio(1);
#pragma unroll
    for (int m = 0; m < 4; ++m)
#pragma unroll
      for (int n = 0; n < NR; ++n)
        acc[m][n] = __builtin_amdgcn_mfma_f32_16x16x32_bf16(afr[m], bfr[n][0], acc[m][n], 0, 0, 0);
    __builtin_amdgcn_s_setprio(0);
    __builtin_amdgcn_sched_barrier(0);
    // ---- phase 1 head: A(kk=1); stage B(u+2) (Bl[p] reads drained at ph0 lgkm) ----
#pragma unroll
    for (int m = 0; m < 4; ++m) afr[m] = readA(p, m, 1);
    if (u + 2 < NT) {
#pragma unroll
      for (int un = 0; un < NB; ++un) stageB(p, un, u + 2);
    }
    __builtin_amdgcn_s_barrier();
    asm volatile("s_waitcnt lgkmcnt(0)" ::: "memory");
    __builtin_amdgcn_sched_barrier(0);
    __builtin_amdgcn_s_setprio(1);
#pragma unroll
    for (int m = 0; m < 4; ++m)
#pragma unroll
      for (int n = 0; n < NR; ++n)
        acc[m][n] = __builtin_amdgcn_mfma_f32_16x16x32_bf16(afr[m], bfr[n][1], acc[m][n], 0, 0, 0);
    __builtin_amdgcn_s_setprio(0);
    __builtin_amdgcn_sched_barrier(0);
    if (u + 2 < NT) { wait_vm<2 * NB>(); }
    else            { wait_vm<0>(); }
    __builtin_amdgcn_s_barrier();
    __builtin_amdgcn_sched_barrier(0);
  }

  const int rbase = tm * 128 + wr * 64, cbase = tn * BN + wc * (NR * 16);
#pragma unroll
  for (int n = 0; n < NR; ++n) {
    int col = cbase + n * 16 + lr;
    float bvl = bias[col];
#pragma unroll
    for (int m = 0; m < 4; ++m) {
#pragma unroll
      for (int rr = 0; rr < 4; ++rr) {
        int row = rbase + m * 16 + lk * 4 + rr;
        float v = acc[m][n][rr] + bvl;
        if (OUT_BF16) ((bf16*)Cp)[(size_t)row * N + col] = (bf16)v;
        else          ((float*)Cp)[(size_t)row * N + col] = v;
      }
    }
  }
}

// ---------------- causal flash attention (R12 proven: double-buffered + fast-path softmax) ----------------
// Q read directly from qkv with RoPE and scale*log2(e) folded; K from kr; V^T from vt.
// Double-buffered K/V prefetch (stage t+1 during compute of t). Fast-path softmax:
// per-thread max + __any ballot; cross-lane max tree + rescale only when running max
// grows >6 (log2 domain); row-sum shfl tree deferred until after PV MFMAs are issued.
// Launch bounds (256,3): proven 112 VGPR, no spill. XCD map: xcd owns bh {4x..4x+3}.
__global__ __launch_bounds__(256, 3)
void attn_kernel(const bf16* __restrict__ qkv, const bf16* __restrict__ Kc,
                 const bf16* __restrict__ Vtg, const float* __restrict__ cost,
                 const float* __restrict__ sint, bf16* __restrict__ O, int S) {
  __shared__ bf16 Kl[2][64 * 128];  // [kv][d], 16B chunks XOR-swizzled by kv&7
  __shared__ bf16 Vt[2][128 * 64];  // [d][kv], 16B chunks XOR-swizzled by d&7
  __shared__ bf16 Pl[4][16 * 64];   // per-wave P, rows XOR-swizzled by row&7
  const int t = threadIdx.x, wid = t >> 6, lane = t & 63;
  const int lr = lane & 15, lk = lane >> 4;
  const int flat = (int)blockIdx.x;
  const int xcd = flat & 7, kk2 = flat >> 3;     // kk2 0..63
  const int bh = xcd * 4 + (kk2 >> 4);           // 4 bh per XCD
  const int b = bh >> 4, h = bh & 15;
  const int NQ = S >> 6;
  const int qtA = kk2 & 15, qtB = NQ - 1 - qtA;
  const int ntA = qtA + 1, ntB = qtB + 1, total = ntA + ntB;  // == NQ+1 for all blocks
  const bf16* Kb = Kc + (size_t)bh * S * 128;
  const bf16* Vb = Vtg + (size_t)bh * 128 * S;
  const float SCL2 = 0.12752040147f;  // (1/sqrt(128)) * log2(e) -> log2-domain logits

  bf16x8 qf[4];
  auto loadQ = [&](int q0) {
    int qrow = q0 + wid * 16 + lr;
    const bf16* qp = qkv + (size_t)(b * 2048 + qrow) * 6144 + h * 128;
    bf16x8 raw[4];
#pragma unroll
    for (int kb = 0; kb < 4; ++kb) raw[kb] = *(const bf16x8*)&qp[kb * 32 + lk * 8];
#pragma unroll
    for (int kb = 0; kb < 4; ++kb) {
      const float* cb = cost + (qrow << 6) + ((kb & 1) << 5) + lk * 8;
      const float* sb = sint + (qrow << 6) + ((kb & 1) << 5) + lk * 8;
#pragma unroll
      for (int j = 0; j < 8; ++j) {
        float qv = (float)raw[kb][j];
        float qo = (float)raw[kb ^ 2][j];
        float rot = (kb < 2) ? -qo : qo;   // d<64 <=> kb<2
        qf[kb][j] = (bf16)((qv * cb[j] + rot * sb[j]) * SCL2);
      }
    }
  };
  auto stage = [&](int buf, int kv0) {
#pragma unroll
    for (int c = 0; c < 4; ++c) {
      int fc = c * 256 + t;
      int kvr = fc >> 4, cc = fc & 15;
      GLD16(Kb + (size_t)(kv0 + kvr) * 128 + (cc ^ (kvr & 7)) * 8, &Kl[buf][fc * 8]);
      int dr = fc >> 3, c2 = fc & 7;
      GLD16(Vb + (size_t)dr * S + kv0 + (c2 ^ (dr & 7)) * 8, &Vt[buf][fc * 8]);
    }
  };

  f32x4 o[8] = {};
  float mrun[4], lrun[4];
#pragma unroll
  for (int r = 0; r < 4; ++r) { mrun[r] = -INFINITY; lrun[r] = 0.f; }

  loadQ(qtA * 64);
  stage(0, 0);
  __syncthreads();  // tile 0 resident
  int cur = 0;
  for (int ti = 0; ti < total; ++ti) {
    if (ti + 1 < total) {
      int tn = ti + 1;
      stage(cur ^ 1, ((tn < ntA) ? tn : tn - ntA) * 64);
    }
    __builtin_amdgcn_sched_barrier(0);
    const bool isA = ti < ntA;
    const int tt = isA ? ti : ti - ntA;
    const int nt = isA ? ntA : ntB;
    const int q0 = (isA ? qtA : qtB) * 64;
    const int kv0 = tt * 64;
    f32x4 sa[4];
    __builtin_amdgcn_s_setprio(1);
#pragma unroll
    for (int n = 0; n < 4; ++n) {
      sa[n] = (f32x4){0.f, 0.f, 0.f, 0.f};
      int kvl = n * 16 + lr;
#pragma unroll
      for (int kb = 0; kb < 4; ++kb) {
        bf16x8 kf = *(const bf16x8*)&Kl[cur][kvl * 128 + (((kb << 2) | lk) ^ (kvl & 7)) * 8];
        sa[n] = __builtin_amdgcn_mfma_f32_16x16x32_bf16(qf[kb], kf, sa[n], 0, 0, 0);
      }
    }
    __builtin_amdgcn_s_setprio(0);
    // ---- fast-path softmax (log2 domain) ----
    float p[4][4];
    float tmax[4] = {-INFINITY, -INFINITY, -INFINITY, -INFINITY};
    const bool lastTile = (tt == nt - 1);
#pragma unroll
    for (int n = 0; n < 4; ++n)
#pragma unroll
      for (int r = 0; r < 4; ++r) {
        float s = sa[n][r];
        if (lastTile) {
          int kvg = kv0 + n * 16 + lr;
          int qg = q0 + wid * 16 + lk * 4 + r;
          if (kvg > qg) s = -INFINITY;
        }
        p[n][r] = s;
        tmax[r] = fmaxf(tmax[r], s);   // per-thread only (4 values)
      }
    bool need = false;
#pragma unroll
    for (int r = 0; r < 4; ++r) need = need || (tmax[r] > mrun[r] + 6.0f);
    if (__any(need)) {   // slow path: full cross-lane max + rescale (rare)
#pragma unroll
      for (int r = 0; r < 4; ++r) {
#pragma unroll
        for (int off = 1; off < 16; off <<= 1)
          tmax[r] = fmaxf(tmax[r], __shfl_xor(tmax[r], off));
        float mnew = fmaxf(mrun[r], tmax[r]);
        float alpha = exp2f(mrun[r] - mnew);
        mrun[r] = mnew;
        lrun[r] *= alpha;
#pragma unroll
        for (int n8 = 0; n8 < 8; ++n8) o[n8][r] *= alpha;
      }
    }
#pragma unroll
    for (int n = 0; n < 4; ++n)
#pragma unroll
      for (int r = 0; r < 4; ++r)
        p[n][r] = exp2f(p[n][r] - mrun[r]);   // bounded by 2^6
    // write P and launch PV immediately (sum tree deferred)
#pragma unroll
    for (int n = 0; n < 4; ++n)
#pragma unroll
      for (int r = 0; r < 4; ++r) {
        int row = lk * 4 + r, col = n * 16 + lr;
        Pl[wid][(row * 64 + col) ^ ((row & 7) << 3)] = (bf16)p[n][r];
      }
    __builtin_amdgcn_s_setprio(1);
#pragma unroll
    for (int kb2 = 0; kb2 < 2; ++kb2) {
      bf16x8 pf = *(const bf16x8*)&Pl[wid][(lr * 64 + kb2 * 32 + lk * 8) ^ ((lr & 7) << 3)];
#pragma unroll
      for (int n8 = 0; n8 < 8; ++n8) {
        int dcol = n8 * 16 + lr;
        bf16x8 vf = *(const bf16x8*)&Vt[cur][(dcol * 64 + kb2 * 32 + lk * 8) ^ ((dcol & 7) << 3)];
        o[n8] = __builtin_amdgcn_mfma_f32_16x16x32_bf16(pf, vf, o[n8], 0, 0, 0);
      }
    }
    __builtin_amdgcn_s_setprio(0);
    // ---- deferred row-sum (overlaps PV on the DS/VALU pipes) ----
    {
      float rsum[4];
#pragma unroll
      for (int r = 0; r < 4; ++r) {
        rsum[r] = (p[0][r] + p[1][r]) + (p[2][r] + p[3][r]);
#pragma unroll
        for (int off = 1; off < 16; off <<= 1)
          rsum[r] += __shfl_xor(rsum[r], off);
        lrun[r] += rsum[r];
      }
    }
    if (ti == ntA - 1) {
#pragma unroll
      for (int r = 0; r < 4; ++r) {
        float rl = 1.0f / lrun[r];
        int row = qtA * 64 + wid * 16 + lk * 4 + r;
        size_t base = ((size_t)(b * S + row)) * 2048 + h * 128;
#pragma unroll
        for (int n8 = 0; n8 < 8; ++n8)
          O[base + n8 * 16 + lr] = (bf16)(o[n8][r] * rl);
      }
#pragma unroll
      for (int n8 = 0; n8 < 8; ++n8) o[n8] = (f32x4){0.f, 0.f, 0.f, 0.f};
#pragma unroll
      for (int r = 0; r < 4; ++r) { mrun[r] = -INFINITY; lrun[r] = 0.f; }
      loadQ(qtB * 64);
    }
    __syncthreads();
    cur ^= 1;
  }
#pragma unroll
  for (int r = 0; r < 4; ++r) {
    float rl = 1.0f / lrun[r];
    int row = qtB * 64 + wid * 16 + lk * 4 + r;
    size_t base = ((size_t)(b * S + row)) * 2048 + h * 128;
#pragma unroll
    for (int n8 = 0; n8 < 8; ++n8)
      O[base + n8 * 16 + lr] = (bf16)(o[n8][r] * rl);
  }
}

// ---------------- launch ----------------

extern "C" void kernel_launch(void* const* d_in, const int* in_sizes, int n_in,
                              void* d_out, int out_size, void* d_ws, size_t ws_size,
                              hipStream_t stream) {
  const float* x  = (const float*)d_in[0];
  const float* Wq = (const float*)d_in[1];
  const float* bq = (const float*)d_in[2];
  const float* Wk = (const float*)d_in[3];
  const float* bk = (const float*)d_in[4];
  const float* Wv = (const float*)d_in[5];
  const float* bv = (const float*)d_in[6];
  const float* Wo = (const float*)d_in[7];
  const float* bo = (const float*)d_in[8];

  char* ws = (char*)d_ws;
  bf16* xb     = (bf16*)(ws);                  // 16 MB (x bf16; reused as attn_out after GEMM1)
  bf16* wqkv   = (bf16*)(ws + 16777216);       // 24 MB (Wq|Wk|Wv bf16, 6144x2048)
  bf16* wob    = (bf16*)(ws + 41943040);       // 8 MB
  bf16* qkv    = (bf16*)(ws + 50331648);       // 50.3 MB, live until attn done
  bf16* kr     = (bf16*)(ws + 100663296);      // 16 MB (RoPE'd K)
  bf16* vt     = (bf16*)(ws + 117440512);      // 16 MB (V^T)
  float* biasq = (float*)(ws + 134217728);     // 24 KB
  float* cost  = (float*)(ws + 134242304);     // 512 KB
  float* sint  = (float*)(ws + 134766592);     // 512 KB (ws end: 135290880)
  bf16* attn_out = xb;                         // alias: x_bf16 dead after GEMM1

  prep_kernel<<<25112, 256, 0, stream>>>(x, Wq, Wk, Wv, Wo, bq, bk, bv,
                                         xb, wqkv, wob, biasq, cost, sint);
  // qkv = x @ [Wq|Wk|Wv]^T + bias  (4096 x 6144 x 2048): 1024 blocks, 2/CU -> 2 rounds
  gemm4w_kernel<192, true><<<1024, 256, 0, stream>>>(xb, wqkv, biasq, qkv, 4096, 6144, 2048);
  rope_tv_kernel<<<6144, 256, 0, stream>>>(qkv, cost, sint, kr, vt);
  attn_kernel<<<512, 256, 0, stream>>>(qkv, kr, vt, cost, sint, attn_out, 2048);
  // out = attn @ Wo^T + bo  (4096 x 2048 x 2048), fp32 out: 512 blocks, 2/CU -> 1 round
  gemm4w_kernel<128, false><<<512, 256, 0, stream>>>(attn_out, wob, bo, (float*)d_out, 4096, 2048, 2048);
}